// Round 1
// baseline (246.042 us; speedup 1.0000x reference)
//
#include <hip/hip_runtime.h>
#include <hip/hip_bf16.h>

typedef __attribute__((ext_vector_type(8))) short short8;
typedef __attribute__((ext_vector_type(4))) short short4_;
typedef __attribute__((ext_vector_type(4))) float f32x4;

__device__ __forceinline__ unsigned short f2bf(float x) {
    union { float f; unsigned u; } v; v.f = x;
    return (unsigned short)((v.u + 0x7FFFu + ((v.u >> 16) & 1u)) >> 16);
}

// ---------------------------------------------------------------------------
// Workspace layout (bytes):
//  wtq  : 64*1024*2   = 131072   @ 0
//  wtkv : 128*1024*2  = 262144   @ 131072   (rows 0-63: Wk col, 64-127: Wv col)
//  Qb   : 4*2048*64*2 = 1048576  @ 393216   (pre-scaled by 0.125, bias folded)
//  Kb   : 4*4096*64*2 = 2097152  @ 1441792
//  Vtb  : 4*64*4096*2 = 2097152  @ 3538944  (V transposed per batch: [b][d][s])
//  total 5636096
// ---------------------------------------------------------------------------
#define WTQ_OFF 0
#define WTKV_OFF 131072
#define Q_OFF 393216
#define K_OFF 1441792
#define VT_OFF 3538944

__global__ __launch_bounds__(256) void prep_weights(
    const float* __restrict__ Wq, const float* __restrict__ Wk,
    const float* __restrict__ Wv, unsigned short* __restrict__ wtq,
    unsigned short* __restrict__ wtkv)
{
    int blk = blockIdx.x;
    int t = threadIdx.x;
    if (blk < 64) {
        int n = blk;
        for (int k = t; k < 1024; k += 256)
            wtq[n * 1024 + k] = f2bf(Wq[k * 64 + n]);
    } else {
        int n = blk - 64;
        const float* src = (n < 64) ? Wk : Wv;
        int c = n & 63;
        for (int k = t; k < 1024; k += 256)
            wtkv[n * 1024 + k] = f2bf(src[k * 64 + c]);
    }
}

// ---------------------------------------------------------------------------
// proj<NOUT>: C[M,NOUT] = A[M,1024] @ W + bias, output bf16.
// M_BLK=32 rows/block, 4 waves each own NOUT/4 cols. BK=64.
// NOUT=128: cols 0-63 -> out0 (K, [row][64]); cols 64-127 -> outT transposed
//           per batch ([b][64][4096]) via LDS tile transpose.
// NOUT=64 : all cols -> out0 (Q), scale=0.125 folds the attention scale.
// ---------------------------------------------------------------------------
template<int NOUT>
__global__ __launch_bounds__(256) void proj_kernel(
    const float* __restrict__ A, const unsigned short* __restrict__ Wt,
    const float* __restrict__ bias0, const float* __restrict__ bias1,
    unsigned short* __restrict__ out0, unsigned short* __restrict__ outT,
    float scale)
{
    constexpr int NPW = NOUT / 4;
    constexpr int NREP = NPW / 16;
    constexpr int AS_BYTES = 32 * 128;
    constexpr int WS_BYTES = NOUT * 128;
    constexpr int VS_BYTES = (NOUT == 128) ? 32 * 128 : 16;
    __shared__ char lds[AS_BYTES + WS_BYTES + VS_BYTES];

    const int t = threadIdx.x;
    const int l = t & 63, w = t >> 6;
    const int r0 = blockIdx.x * 32;

    f32x4 acc[2][NREP];
    #pragma unroll
    for (int m = 0; m < 2; ++m)
        #pragma unroll
        for (int n = 0; n < NREP; ++n)
            acc[m][n] = (f32x4){0.f, 0.f, 0.f, 0.f};

    for (int kt = 0; kt < 16; ++kt) {
        const int k0 = kt * 64;
        __syncthreads();
        // stage A tile: 32 rows x 64 k, fp32 -> bf16, XOR-swizzled
        #pragma unroll
        for (int i = 0; i < 2; ++i) {
            int id = t + i * 256;              // 0..511
            int row = id >> 4, c4 = id & 15;
            float4 v = *(const float4*)(A + (size_t)(r0 + row) * 1024 + k0 + c4 * 4);
            short4_ pk = { (short)f2bf(v.x), (short)f2bf(v.y),
                           (short)f2bf(v.z), (short)f2bf(v.w) };
            int off = row * 128 + ((c4 * 8) ^ ((row & 7) << 4));
            *(short4_*)(lds + off) = pk;
        }
        // stage Wt tile: NOUT rows x 64 k bf16, XOR-swizzled
        #pragma unroll
        for (int i = 0; i < NOUT / 32; ++i) {
            int id = t + i * 256;
            int n = id >> 3, c8 = id & 7;
            short8 v = *(const short8*)(Wt + (size_t)n * 1024 + k0 + c8 * 8);
            int off = AS_BYTES + n * 128 + ((c8 * 16) ^ ((n & 7) << 4));
            *(short8*)(lds + off) = v;
        }
        __syncthreads();
        #pragma unroll
        for (int ks = 0; ks < 2; ++ks) {
            int kb = (ks * 32 + ((l >> 4) * 8)) * 2;   // k byte offset in row
            short8 a[2], bfr[NREP];
            #pragma unroll
            for (int m = 0; m < 2; ++m) {
                int row = m * 16 + (l & 15);
                a[m] = *(short8*)(lds + row * 128 + (kb ^ ((row & 7) << 4)));
            }
            #pragma unroll
            for (int n = 0; n < NREP; ++n) {
                int wr = w * NPW + n * 16 + (l & 15);
                bfr[n] = *(short8*)(lds + AS_BYTES + wr * 128 + (kb ^ ((wr & 7) << 4)));
            }
            #pragma unroll
            for (int m = 0; m < 2; ++m)
                #pragma unroll
                for (int n = 0; n < NREP; ++n)
                    acc[m][n] = __builtin_amdgcn_mfma_f32_16x16x32_bf16(
                        a[m], bfr[n], acc[m][n], 0, 0, 0);
        }
    }

    // epilogue: row = r0 + m*16 + (l>>4)*4 + i ; col = w*NPW + n*16 + (l&15)
    #pragma unroll
    for (int m = 0; m < 2; ++m) {
        #pragma unroll
        for (int n = 0; n < NREP; ++n) {
            int col = w * NPW + n * 16 + (l & 15);
            float bsv = (NOUT == 128) ? ((col < 64) ? bias0[col] : bias1[col - 64])
                                      : bias0[col];
            #pragma unroll
            for (int i = 0; i < 4; ++i) {
                int lrow = m * 16 + ((l >> 4) * 4) + i;
                float val = (acc[m][n][i] + bsv) * scale;
                unsigned short bb = f2bf(val);
                if (NOUT == 64 || col < 64) {
                    out0[(size_t)(r0 + lrow) * 64 + col] = bb;
                } else {
                    *(unsigned short*)(lds + AS_BYTES + WS_BYTES + lrow * 128
                                       + (col - 64) * 2) = bb;
                }
            }
        }
    }
    if (NOUT == 128) {
        __syncthreads();
        // cooperative transposed store: Vt[b][d][s0+s]
        int d = t >> 2, sc = (t & 3) * 8;
        short8 vals;
        #pragma unroll
        for (int j = 0; j < 8; ++j)
            vals[j] = *(short*)(lds + AS_BYTES + WS_BYTES + (sc + j) * 128 + d * 2);
        int b = r0 >> 12, s0 = r0 & 4095;
        *(short8*)(outT + (((size_t)(b * 64 + d)) << 12) + s0 + sc) = vals;
    }
}

// ---------------------------------------------------------------------------
// Flash attention: grid (64 qtiles, 4 batches), 256 threads = 4 waves.
// Wave w: 32 Q-rows (shared), private key-chunk [w*1024, w*1024+1024),
// KT=32 tiles, per-wave LDS (no in-loop barriers). Exact cross-wave combine.
// ---------------------------------------------------------------------------
__global__ __launch_bounds__(256) void attn_kernel(
    const unsigned short* __restrict__ Qb, const unsigned short* __restrict__ Kb,
    const unsigned short* __restrict__ Vtb, float* __restrict__ Out)
{
    __shared__ char lds[40960];
    const int t = threadIdx.x;
    const int l = t & 63, w = t >> 6;
    const int b = blockIdx.y;
    const int q0 = blockIdx.x * 32;

    char* Ks = lds + w * 10240;    // [32 keys][128B] swizzled
    char* Vs = Ks + 4096;          // [64 d][64B] swizzled
    char* Ps = Ks + 8192;          // [32 q][64B] swizzled

    // Q fragments (A-operand): row = l&15, k(d) = ks*32 + (l>>4)*8
    short8 qf[2][2];
    #pragma unroll
    for (int m = 0; m < 2; ++m)
        #pragma unroll
        for (int ks = 0; ks < 2; ++ks)
            qf[m][ks] = *(const short8*)(Qb
                + (size_t)(b * 2048 + q0 + m * 16 + (l & 15)) * 64
                + ks * 32 + (l >> 4) * 8);

    f32x4 o[2][4];
    #pragma unroll
    for (int m = 0; m < 2; ++m)
        #pragma unroll
        for (int n = 0; n < 4; ++n)
            o[m][n] = (f32x4){0.f, 0.f, 0.f, 0.f};
    float m_run[2][4], l_run[2][4];
    #pragma unroll
    for (int m = 0; m < 2; ++m)
        #pragma unroll
        for (int i = 0; i < 4; ++i) { m_run[m][i] = -INFINITY; l_run[m][i] = 0.f; }

    const size_t kbase = (size_t)b * 4096 * 64;
    const size_t vbase = (size_t)b * 64 * 4096;

    for (int tile = 0; tile < 32; ++tile) {
        const int kt = w * 1024 + tile * 32;
        // stage K tile (32 keys x 64 d)
        #pragma unroll
        for (int c = 0; c < 4; ++c) {
            int ci = c * 64 + l;
            int key = ci >> 3, c8 = ci & 7;
            short8 v = *(const short8*)(Kb + kbase + (size_t)(kt + key) * 64 + c8 * 8);
            *(short8*)(Ks + key * 128 + ((c8 * 16) ^ ((key & 7) << 4))) = v;
        }
        // stage Vt tile (64 d x 32 keys)
        #pragma unroll
        for (int c = 0; c < 4; ++c) {
            int ci = c * 64 + l;
            int d = ci >> 2, kc = ci & 3;
            short8 v = *(const short8*)(Vtb + vbase + (size_t)d * 4096 + kt + kc * 8);
            *(short8*)(Vs + d * 64 + ((kc * 16) ^ ((d & 3) << 4))) = v;
        }
        // S = Q K^T  (C: col=key=l&15, row=q=(l>>4)*4+i)
        f32x4 s[2][2];
        #pragma unroll
        for (int m = 0; m < 2; ++m)
            #pragma unroll
            for (int n = 0; n < 2; ++n)
                s[m][n] = (f32x4){0.f, 0.f, 0.f, 0.f};
        #pragma unroll
        for (int ks = 0; ks < 2; ++ks) {
            int kb2 = (ks * 32 + (l >> 4) * 8) * 2;
            #pragma unroll
            for (int n = 0; n < 2; ++n) {
                int kr = n * 16 + (l & 15);
                short8 kf = *(short8*)(Ks + kr * 128 + (kb2 ^ ((kr & 7) << 4)));
                #pragma unroll
                for (int m = 0; m < 2; ++m)
                    s[m][n] = __builtin_amdgcn_mfma_f32_16x16x32_bf16(
                        qf[m][ks], kf, s[m][n], 0, 0, 0);
            }
        }
        // online softmax (fp32), P -> bf16 LDS
        #pragma unroll
        for (int m = 0; m < 2; ++m) {
            #pragma unroll
            for (int i = 0; i < 4; ++i) {
                float pm = fmaxf(s[m][0][i], s[m][1][i]);
                pm = fmaxf(pm, __shfl_xor(pm, 1));
                pm = fmaxf(pm, __shfl_xor(pm, 2));
                pm = fmaxf(pm, __shfl_xor(pm, 4));
                pm = fmaxf(pm, __shfl_xor(pm, 8));
                float mo = m_run[m][i];
                float mn = fmaxf(mo, pm);
                m_run[m][i] = mn;
                float corr = __expf(mo - mn);
                float p0 = __expf(s[m][0][i] - mn);
                float p1 = __expf(s[m][1][i] - mn);
                float rs = p0 + p1;
                rs += __shfl_xor(rs, 1);
                rs += __shfl_xor(rs, 2);
                rs += __shfl_xor(rs, 4);
                rs += __shfl_xor(rs, 8);
                l_run[m][i] = l_run[m][i] * corr + rs;
                #pragma unroll
                for (int n = 0; n < 4; ++n) o[m][n][i] *= corr;
                int prow = m * 16 + (l >> 4) * 4 + i;
                int c0 = (l & 15) * 2;
                *(unsigned short*)(Ps + prow * 64 + (c0 ^ ((prow & 3) << 4))) = f2bf(p0);
                int c1 = (16 + (l & 15)) * 2;
                *(unsigned short*)(Ps + prow * 64 + (c1 ^ ((prow & 3) << 4))) = f2bf(p1);
            }
        }
        // O += P V
        #pragma unroll
        for (int m = 0; m < 2; ++m) {
            int prow = m * 16 + (l & 15);
            short8 pa = *(short8*)(Ps + prow * 64 + (((l >> 4) * 16) ^ ((prow & 3) << 4)));
            #pragma unroll
            for (int n = 0; n < 4; ++n) {
                int vr = n * 16 + (l & 15);
                short8 vf = *(short8*)(Vs + vr * 64 + (((l >> 4) * 16) ^ ((vr & 3) << 4)));
                o[m][n] = __builtin_amdgcn_mfma_f32_16x16x32_bf16(pa, vf, o[m][n], 0, 0, 0);
            }
        }
    }

    __syncthreads();
    // cross-wave combine (exact): stage O, m, l into LDS
    float* Oc = (float*)lds;               // [4][32][64]
    float* ml = (float*)(lds + 32768);     // [4][2][32]
    #pragma unroll
    for (int m = 0; m < 2; ++m)
        #pragma unroll
        for (int n = 0; n < 4; ++n)
            #pragma unroll
            for (int i = 0; i < 4; ++i) {
                int row = m * 16 + (l >> 4) * 4 + i;
                int d = n * 16 + (l & 15);
                Oc[(w * 32 + row) * 64 + d] = o[m][n][i];
            }
    if ((l & 15) == 0) {
        #pragma unroll
        for (int m = 0; m < 2; ++m)
            #pragma unroll
            for (int i = 0; i < 4; ++i) {
                int row = m * 16 + (l >> 4) * 4 + i;
                ml[w * 64 + row] = m_run[m][i];
                ml[w * 64 + 32 + row] = l_run[m][i];
            }
    }
    __syncthreads();
    {
        int row = t >> 3, dc = (t & 7) * 8;
        float mw[4], M = -INFINITY;
        #pragma unroll
        for (int ww = 0; ww < 4; ++ww) { mw[ww] = ml[ww * 64 + row]; M = fmaxf(M, mw[ww]); }
        float sc4[4], L = 0.f;
        #pragma unroll
        for (int ww = 0; ww < 4; ++ww) {
            sc4[ww] = __expf(mw[ww] - M);
            L += ml[ww * 64 + 32 + row] * sc4[ww];
        }
        float inv = 1.0f / L;
        float vals[8];
        #pragma unroll
        for (int j = 0; j < 8; ++j) {
            float a = 0.f;
            #pragma unroll
            for (int ww = 0; ww < 4; ++ww)
                a += Oc[(ww * 32 + row) * 64 + dc + j] * sc4[ww];
            vals[j] = a * inv;
        }
        float* dst = Out + (size_t)(b * 2048 + q0 + row) * 64 + dc;
        *(float4*)(dst) = make_float4(vals[0], vals[1], vals[2], vals[3]);
        *(float4*)(dst + 4) = make_float4(vals[4], vals[5], vals[6], vals[7]);
    }
}

extern "C" void kernel_launch(void* const* d_in, const int* in_sizes, int n_in,
                              void* d_out, int out_size, void* d_ws, size_t ws_size,
                              hipStream_t stream) {
    const float* enc = (const float*)d_in[0];   // [4,4096,1024]
    const float* dec = (const float*)d_in[1];   // [4,2048,1024]
    const float* Wq  = (const float*)d_in[2];
    const float* bq  = (const float*)d_in[3];
    const float* Wk  = (const float*)d_in[4];
    const float* bk  = (const float*)d_in[5];
    const float* Wv  = (const float*)d_in[6];
    const float* bv  = (const float*)d_in[7];

    char* ws = (char*)d_ws;
    unsigned short* wtq  = (unsigned short*)(ws + WTQ_OFF);
    unsigned short* wtkv = (unsigned short*)(ws + WTKV_OFF);
    unsigned short* Qb   = (unsigned short*)(ws + Q_OFF);
    unsigned short* Kb   = (unsigned short*)(ws + K_OFF);
    unsigned short* Vtb  = (unsigned short*)(ws + VT_OFF);

    prep_weights<<<192, 256, 0, stream>>>(Wq, Wk, Wv, wtq, wtkv);
    // enc -> K (+bias) and V^T (+bias); read enc once
    proj_kernel<128><<<512, 256, 0, stream>>>(enc, wtkv, bk, bv, Kb, Vtb, 1.0f);
    // dec -> Q, fold 1/sqrt(64) into Q (and bias)
    proj_kernel<64><<<256, 256, 0, stream>>>(dec, wtq, bq, bq, Qb, (unsigned short*)nullptr, 0.125f);
    attn_kernel<<<dim3(64, 4), 256, 0, stream>>>(Qb, Kb, Vtb, (float*)d_out);
}

// Round 2
// 204.311 us; speedup vs baseline: 1.2043x; 1.2043x over previous
//
#include <hip/hip_runtime.h>
#include <hip/hip_bf16.h>

typedef __attribute__((ext_vector_type(8))) short short8;
typedef __attribute__((ext_vector_type(4))) float f32x4;
typedef unsigned short u16;

__device__ __forceinline__ u16 f2bf(float x) {
    union { float f; unsigned u; } v; v.f = x;
    return (u16)((v.u + 0x7FFFu + ((v.u >> 16) & 1u)) >> 16);
}

__device__ __forceinline__ void gl_lds16(const void* g, void* l) {
    __builtin_amdgcn_global_load_lds(
        (const __attribute__((address_space(1))) unsigned int*)g,
        (__attribute__((address_space(3))) unsigned int*)l, 16, 0, 0);
}

// ---------------------------------------------------------------------------
// Workspace layout (bytes):
//  wtq   @ 0        : 64*1024*2   = 131072
//  wtkv  @ 131072   : 128*1024*2  = 262144  (rows 0-63 = Wk^T, 64-127 = Wv^T)
//  Qb    @ 393216   : 4*2048*64*2 = 1048576 (pre-scaled 0.125, bias folded)
//  Kb    @ 1441792  : 4*4096*64*2 = 2097152
//  Vtb   @ 3538944  : 4*64*4096*2 = 2097152 ([b][d][s])
//  Opart @ 5636096  : 4*8192*64*4 = 8388608 (split-k partial O, unnormalized)
//  Mpart @ 14024704 : 4*8192*4    = 131072
//  Lpart @ 14155776 : 4*8192*4    = 131072
//  total 14286848
// ---------------------------------------------------------------------------
#define WTQ_OFF   0
#define WTKV_OFF  131072
#define Q_OFF     393216
#define K_OFF     1441792
#define VT_OFF    3538944
#define OPART_OFF 5636096
#define MPART_OFF 14024704
#define LPART_OFF 14155776

// ---------------------------------------------------------------------------
// prep2: W [1024][64] f32 -> W^T [64][1024] bf16, coalesced via LDS tile.
// grid 48: mat = blk>>4 (Wq/Wk/Wv), kc = blk&15 (64-row k chunk).
// ---------------------------------------------------------------------------
__global__ __launch_bounds__(256) void prep2(
    const float* __restrict__ Wq, const float* __restrict__ Wk,
    const float* __restrict__ Wv, u16* __restrict__ wtq, u16* __restrict__ wtkv)
{
    __shared__ u16 tile[64][66];
    const int t = threadIdx.x;
    const int mat = blockIdx.x >> 4, kc = blockIdx.x & 15;
    const float* src = (mat == 0) ? Wq : ((mat == 1) ? Wk : Wv);
    u16* dst = (mat == 0) ? wtq : (wtkv + ((mat == 2) ? 64 * 1024 : 0));
    #pragma unroll
    for (int c = 0; c < 4; ++c) {
        int id = t + c * 256;
        int r = id >> 4, c4 = id & 15;
        float4 v = *(const float4*)(src + (size_t)(kc * 64 + r) * 64 + c4 * 4);
        tile[r][c4 * 4 + 0] = f2bf(v.x);
        tile[r][c4 * 4 + 1] = f2bf(v.y);
        tile[r][c4 * 4 + 2] = f2bf(v.z);
        tile[r][c4 * 4 + 3] = f2bf(v.w);
    }
    __syncthreads();
    int n = t >> 2, kch = t & 3;
    short8 v0, v1;
    #pragma unroll
    for (int j = 0; j < 8; ++j) {
        v0[j] = (short)tile[kch * 16 + j][n];
        v1[j] = (short)tile[kch * 16 + 8 + j][n];
    }
    u16* dp = dst + (size_t)n * 1024 + kc * 64 + kch * 16;
    *(short8*)dp = v0;
    *(short8*)(dp + 8) = v1;
}

// ---------------------------------------------------------------------------
// proj2<NOUT>: C[M,NOUT] = A[M,1024] @ W^T + bias -> bf16. BM=64, BK=64,
// 4 waves (2m x 2n). Double-buffered global_load_lds staging: A fp32
// (source-XOR-swizzled, converted at fragment build), W bf16.
// NOUT=128: wn=0 cols -> K [row][64]; wn=1 cols -> V^T [b][d][s] via LDS.
// NOUT=64 : Q, scale=0.125 folds attention scale.
// ---------------------------------------------------------------------------
template<int NOUT>
__global__ __launch_bounds__(256) void proj2(
    const float* __restrict__ A, const u16* __restrict__ Wt,
    const float* __restrict__ bias0, const float* __restrict__ bias1,
    u16* __restrict__ out0, u16* __restrict__ outT, float scale)
{
    constexpr int NREP = NOUT / 32;        // n-frags per wave
    constexpr int WCH = NOUT / 32;         // W stage chunks of 256 lanes
    constexpr int ABYTES = 64 * 64 * 4;    // 16 KB fp32 A tile
    constexpr int WBYTES = NOUT * 64 * 2;  // W tile
    constexpr int BUF = ABYTES + WBYTES;
    __shared__ __align__(16) char lds[2 * BUF];

    const int t = threadIdx.x, l = t & 63, w = t >> 6;
    const int wm = w >> 1, wn = w & 1;
    const int r0 = blockIdx.x * 64;

    f32x4 acc[2][NREP];
    #pragma unroll
    for (int m = 0; m < 2; ++m)
        #pragma unroll
        for (int n = 0; n < NREP; ++n)
            acc[m][n] = (f32x4){0.f, 0.f, 0.f, 0.f};

    auto stage = [&](int buf, int kt) {
        char* Ab = lds + buf * BUF;
        char* Wb = Ab + ABYTES;
        const int k0 = kt * 64;
        #pragma unroll
        for (int c = 0; c < 4; ++c) {
            int id = t + c * 256;           // 0..1023
            int row = id >> 4, sl = id & 15;
            int k4 = sl ^ (row & 7);        // source pre-swizzle -> swizzled LDS
            gl_lds16(A + (size_t)(r0 + row) * 1024 + k0 + k4 * 4, Ab + id * 16);
        }
        #pragma unroll
        for (int c = 0; c < WCH; ++c) {
            int id = t + c * 256;
            int row = id >> 3, sl = id & 7;
            int c8 = sl ^ (row & 7);
            gl_lds16(Wt + (size_t)row * 1024 + k0 + c8 * 8, Wb + id * 16);
        }
    };

    stage(0, 0);
    __syncthreads();
    int cur = 0;
    for (int kt = 0; kt < 16; ++kt) {
        if (kt < 15) stage(cur ^ 1, kt + 1);
        const char* Ab = lds + cur * BUF;
        const char* Wb = Ab + ABYTES;
        #pragma unroll
        for (int ks = 0; ks < 2; ++ks) {
            short8 afr[2], bfr[NREP];
            #pragma unroll
            for (int m = 0; m < 2; ++m) {
                int row = wm * 32 + m * 16 + (l & 15);
                int s0 = ks * 8 + (l >> 4) * 2;   // 16B slot of first 4 floats
                f32x4 lo = *(const f32x4*)(Ab + row * 256 + ((s0 ^ (row & 7)) << 4));
                f32x4 hi = *(const f32x4*)(Ab + row * 256 + (((s0 + 1) ^ (row & 7)) << 4));
                short8 r;
                r[0] = (short)f2bf(lo[0]); r[1] = (short)f2bf(lo[1]);
                r[2] = (short)f2bf(lo[2]); r[3] = (short)f2bf(lo[3]);
                r[4] = (short)f2bf(hi[0]); r[5] = (short)f2bf(hi[1]);
                r[6] = (short)f2bf(hi[2]); r[7] = (short)f2bf(hi[3]);
                afr[m] = r;
            }
            #pragma unroll
            for (int n = 0; n < NREP; ++n) {
                int row = wn * (NOUT / 2) + n * 16 + (l & 15);
                int c8 = ks * 4 + (l >> 4);
                bfr[n] = *(const short8*)(Wb + row * 128 + ((c8 ^ (row & 7)) << 4));
            }
            #pragma unroll
            for (int m = 0; m < 2; ++m)
                #pragma unroll
                for (int n = 0; n < NREP; ++n)
                    acc[m][n] = __builtin_amdgcn_mfma_f32_16x16x32_bf16(
                        afr[m], bfr[n], acc[m][n], 0, 0, 0);
        }
        __syncthreads();
        cur ^= 1;
    }

    // epilogue: lrow = wm*32 + m*16 + (l>>4)*4 + i ; col = wn*(NOUT/2) + n*16 + (l&15)
    u16* Vs2 = (u16*)lds;   // reuse buf0 (free after last barrier)
    #pragma unroll
    for (int m = 0; m < 2; ++m) {
        #pragma unroll
        for (int n = 0; n < NREP; ++n) {
            int col = wn * (NOUT / 2) + n * 16 + (l & 15);
            #pragma unroll
            for (int i = 0; i < 4; ++i) {
                int lrow = wm * 32 + m * 16 + (l >> 4) * 4 + i;
                if (NOUT == 64 || wn == 0) {
                    float val = (acc[m][n][i] + bias0[col]) * scale;
                    out0[(size_t)(r0 + lrow) * 64 + col] = f2bf(val);
                } else {
                    int d = col - 64;
                    float val = (acc[m][n][i] + bias1[d]) * scale;
                    Vs2[lrow * 66 + d] = f2bf(val);
                }
            }
        }
    }
    if (NOUT == 128) {
        __syncthreads();
        int d = t >> 2, sch = t & 3;
        short8 v0, v1;
        #pragma unroll
        for (int j = 0; j < 8; ++j) {
            v0[j] = (short)Vs2[(sch * 16 + j) * 66 + d];
            v1[j] = (short)Vs2[(sch * 16 + 8 + j) * 66 + d];
        }
        int b = r0 >> 12, s0 = r0 & 4095;
        u16* dp = outT + (((size_t)(b * 64 + d)) << 12) + s0 + sch * 16;
        *(short8*)dp = v0;
        *(short8*)(dp + 8) = v1;
    }
}

// ---------------------------------------------------------------------------
// Flash attention, split-K: grid (64 qtiles, 4 batch, 4 ksplit), 4 waves.
// Wave w: 32 shared Q-rows, private 256-key chunk, 8 tiles of 32 keys.
// Per-wave LDS (no in-loop barriers): Ks 32x128B XOR-swz (global_load_lds,
// pre-swizzled source); Vs 64 rows stride 80 (pad-16); Ps aliases Ks
// (P written after K reads complete, dead before next K stage).
// Block writes unnormalized partial O + (M,L); attn_combine reduces splits.
// ---------------------------------------------------------------------------
__global__ __launch_bounds__(256) void attn_kernel(
    const u16* __restrict__ Qb, const u16* __restrict__ Kb,
    const u16* __restrict__ Vtb, float* __restrict__ Opart,
    float* __restrict__ Mpart, float* __restrict__ Lpart)
{
    __shared__ __align__(16) char lds[36864];
    const int t = threadIdx.x;
    const int l = t & 63, w = t >> 6;
    const int b = blockIdx.y, bz = blockIdx.z;
    const int q0 = blockIdx.x * 32;

    char* Ks = lds + w * 9216;     // [32 keys][128B] XOR-swizzled
    char* Vs = Ks + 4096;          // [64 d][80B] pad-16
    char* Ps = Ks;                 // [32 q][80B] pad-16, aliases Ks

    short8 qf[2][2];
    #pragma unroll
    for (int m = 0; m < 2; ++m)
        #pragma unroll
        for (int ks = 0; ks < 2; ++ks)
            qf[m][ks] = *(const short8*)(Qb
                + (size_t)(b * 2048 + q0 + m * 16 + (l & 15)) * 64
                + ks * 32 + (l >> 4) * 8);

    f32x4 o[2][4];
    #pragma unroll
    for (int m = 0; m < 2; ++m)
        #pragma unroll
        for (int n = 0; n < 4; ++n)
            o[m][n] = (f32x4){0.f, 0.f, 0.f, 0.f};
    float m_run[2][4], l_run[2][4];
    #pragma unroll
    for (int m = 0; m < 2; ++m)
        #pragma unroll
        for (int i = 0; i < 4; ++i) { m_run[m][i] = -INFINITY; l_run[m][i] = 0.f; }

    const size_t kbase = (size_t)b * 4096 * 64;
    const size_t vbase = (size_t)b * 64 * 4096;
    const int kt0 = bz * 1024 + w * 256;

    for (int tile = 0; tile < 8; ++tile) {
        const int kt = kt0 + tile * 32;
        // K tile via global_load_lds (linear LDS dest, pre-swizzled source)
        #pragma unroll
        for (int c = 0; c < 4; ++c) {
            int id = c * 64 + l;
            int key = id >> 3, sl = id & 7;
            int c8 = sl ^ (key & 7);
            gl_lds16(Kb + kbase + (size_t)(kt + key) * 64 + c8 * 8, Ks + id * 16);
        }
        // V tile reg->LDS, stride-80 rows
        #pragma unroll
        for (int c = 0; c < 4; ++c) {
            int ci = c * 64 + l;
            int d = ci >> 2, kc = ci & 3;
            short8 v = *(const short8*)(Vtb + vbase + (size_t)d * 4096 + kt + kc * 8);
            *(short8*)(Vs + d * 80 + kc * 16) = v;
        }
        asm volatile("s_waitcnt vmcnt(0)" ::: "memory");   // K gload_lds done
        // S = Q K^T
        f32x4 s[2][2];
        #pragma unroll
        for (int m = 0; m < 2; ++m)
            #pragma unroll
            for (int n = 0; n < 2; ++n)
                s[m][n] = (f32x4){0.f, 0.f, 0.f, 0.f};
        #pragma unroll
        for (int ks = 0; ks < 2; ++ks) {
            int sl8 = ks * 4 + (l >> 4);
            #pragma unroll
            for (int n = 0; n < 2; ++n) {
                int kr = n * 16 + (l & 15);
                short8 kf = *(const short8*)(Ks + kr * 128 + ((sl8 ^ (kr & 7)) << 4));
                #pragma unroll
                for (int m = 0; m < 2; ++m)
                    s[m][n] = __builtin_amdgcn_mfma_f32_16x16x32_bf16(
                        qf[m][ks], kf, s[m][n], 0, 0, 0);
            }
        }
        // online softmax, P -> bf16 LDS (stride 80)
        #pragma unroll
        for (int m = 0; m < 2; ++m) {
            #pragma unroll
            for (int i = 0; i < 4; ++i) {
                float pm = fmaxf(s[m][0][i], s[m][1][i]);
                pm = fmaxf(pm, __shfl_xor(pm, 1));
                pm = fmaxf(pm, __shfl_xor(pm, 2));
                pm = fmaxf(pm, __shfl_xor(pm, 4));
                pm = fmaxf(pm, __shfl_xor(pm, 8));
                float mo = m_run[m][i];
                float mn = fmaxf(mo, pm);
                m_run[m][i] = mn;
                float corr = __expf(mo - mn);
                float p0 = __expf(s[m][0][i] - mn);
                float p1 = __expf(s[m][1][i] - mn);
                float rs = p0 + p1;
                rs += __shfl_xor(rs, 1);
                rs += __shfl_xor(rs, 2);
                rs += __shfl_xor(rs, 4);
                rs += __shfl_xor(rs, 8);
                l_run[m][i] = l_run[m][i] * corr + rs;
                #pragma unroll
                for (int n = 0; n < 4; ++n) o[m][n][i] *= corr;
                int prow = m * 16 + (l >> 4) * 4 + i;
                *(u16*)(Ps + prow * 80 + (l & 15) * 2) = f2bf(p0);
                *(u16*)(Ps + prow * 80 + 32 + (l & 15) * 2) = f2bf(p1);
            }
        }
        // O += P V
        #pragma unroll
        for (int m = 0; m < 2; ++m) {
            int prow = m * 16 + (l & 15);
            short8 pa = *(const short8*)(Ps + prow * 80 + (l >> 4) * 16);
            #pragma unroll
            for (int n = 0; n < 4; ++n) {
                int vr = n * 16 + (l & 15);
                short8 vf = *(const short8*)(Vs + vr * 80 + (l >> 4) * 16);
                o[m][n] = __builtin_amdgcn_mfma_f32_16x16x32_bf16(pa, vf, o[m][n], 0, 0, 0);
            }
        }
    }

    __syncthreads();
    // block combine (4 waves, exact) -> unnormalized partial + (M, L)
    float* Oc = (float*)lds;               // [4][32][64]
    float* ml = (float*)(lds + 32768);     // [4][2][32]
    #pragma unroll
    for (int m = 0; m < 2; ++m)
        #pragma unroll
        for (int n = 0; n < 4; ++n)
            #pragma unroll
            for (int i = 0; i < 4; ++i) {
                int row = m * 16 + (l >> 4) * 4 + i;
                int d = n * 16 + (l & 15);
                Oc[(w * 32 + row) * 64 + d] = o[m][n][i];
            }
    if ((l & 15) == 0) {
        #pragma unroll
        for (int m = 0; m < 2; ++m)
            #pragma unroll
            for (int i = 0; i < 4; ++i) {
                int row = m * 16 + (l >> 4) * 4 + i;
                ml[w * 64 + row] = m_run[m][i];
                ml[w * 64 + 32 + row] = l_run[m][i];
            }
    }
    __syncthreads();
    {
        int row = t >> 3, dc = (t & 7) * 8;
        float mw[4], M = -INFINITY;
        #pragma unroll
        for (int ww = 0; ww < 4; ++ww) { mw[ww] = ml[ww * 64 + row]; M = fmaxf(M, mw[ww]); }
        float sc4[4], L = 0.f;
        #pragma unroll
        for (int ww = 0; ww < 4; ++ww) {
            sc4[ww] = __expf(mw[ww] - M);
            L += ml[ww * 64 + 32 + row] * sc4[ww];
        }
        float vals[8];
        #pragma unroll
        for (int j = 0; j < 8; ++j) {
            float a = 0.f;
            #pragma unroll
            for (int ww = 0; ww < 4; ++ww)
                a += Oc[(ww * 32 + row) * 64 + dc + j] * sc4[ww];
            vals[j] = a;
        }
        size_t gq = (size_t)b * 2048 + q0 + row;
        float* op = Opart + ((size_t)bz * 8192 + gq) * 64 + dc;
        *(float4*)op = make_float4(vals[0], vals[1], vals[2], vals[3]);
        *(float4*)(op + 4) = make_float4(vals[4], vals[5], vals[6], vals[7]);
        if ((t & 7) == 0) {
            Mpart[bz * 8192 + gq] = M;
            Lpart[bz * 8192 + gq] = L;
        }
    }
}

// ---------------------------------------------------------------------------
// Combine 4 key-splits: out = sum_ks Opart*e^(M_ks-M*) / sum_ks L_ks*e^(M_ks-M*)
// ---------------------------------------------------------------------------
__global__ __launch_bounds__(256) void attn_combine(
    const float* __restrict__ Opart, const float* __restrict__ Mpart,
    const float* __restrict__ Lpart, float* __restrict__ Out)
{
    int idx = blockIdx.x * 256 + threadIdx.x;
    int row = idx >> 3, dc = (idx & 7) * 8;
    float mv[4], M = -INFINITY;
    #pragma unroll
    for (int ks = 0; ks < 4; ++ks) { mv[ks] = Mpart[ks * 8192 + row]; M = fmaxf(M, mv[ks]); }
    float wk[4], L = 0.f;
    #pragma unroll
    for (int ks = 0; ks < 4; ++ks) {
        wk[ks] = __expf(mv[ks] - M);
        L += Lpart[ks * 8192 + row] * wk[ks];
    }
    float inv = 1.0f / L;
    float o[8] = {0.f, 0.f, 0.f, 0.f, 0.f, 0.f, 0.f, 0.f};
    #pragma unroll
    for (int ks = 0; ks < 4; ++ks) {
        const float* p = Opart + ((size_t)ks * 8192 + row) * 64 + dc;
        float4 a = *(const float4*)p;
        float4 bb = *(const float4*)(p + 4);
        o[0] += a.x * wk[ks]; o[1] += a.y * wk[ks];
        o[2] += a.z * wk[ks]; o[3] += a.w * wk[ks];
        o[4] += bb.x * wk[ks]; o[5] += bb.y * wk[ks];
        o[6] += bb.z * wk[ks]; o[7] += bb.w * wk[ks];
    }
    float* dst = Out + (size_t)row * 64 + dc;
    *(float4*)dst = make_float4(o[0] * inv, o[1] * inv, o[2] * inv, o[3] * inv);
    *(float4*)(dst + 4) = make_float4(o[4] * inv, o[5] * inv, o[6] * inv, o[7] * inv);
}

extern "C" void kernel_launch(void* const* d_in, const int* in_sizes, int n_in,
                              void* d_out, int out_size, void* d_ws, size_t ws_size,
                              hipStream_t stream) {
    const float* enc = (const float*)d_in[0];   // [4,4096,1024]
    const float* dec = (const float*)d_in[1];   // [4,2048,1024]
    const float* Wq  = (const float*)d_in[2];
    const float* bq  = (const float*)d_in[3];
    const float* Wk  = (const float*)d_in[4];
    const float* bk  = (const float*)d_in[5];
    const float* Wv  = (const float*)d_in[6];
    const float* bv  = (const float*)d_in[7];

    char* ws = (char*)d_ws;
    u16* wtq    = (u16*)(ws + WTQ_OFF);
    u16* wtkv   = (u16*)(ws + WTKV_OFF);
    u16* Qb     = (u16*)(ws + Q_OFF);
    u16* Kb     = (u16*)(ws + K_OFF);
    u16* Vtb    = (u16*)(ws + VT_OFF);
    float* Opart = (float*)(ws + OPART_OFF);
    float* Mpart = (float*)(ws + MPART_OFF);
    float* Lpart = (float*)(ws + LPART_OFF);

    prep2<<<48, 256, 0, stream>>>(Wq, Wk, Wv, wtq, wtkv);
    proj2<128><<<256, 256, 0, stream>>>(enc, wtkv, bk, bv, Kb, Vtb, 1.0f);
    proj2<64><<<128, 256, 0, stream>>>(dec, wtq, bq, bq, Qb, (u16*)nullptr, 0.125f);
    attn_kernel<<<dim3(64, 4, 4), 256, 0, stream>>>(Qb, Kb, Vtb, Opart, Mpart, Lpart);
    attn_combine<<<256, 256, 0, stream>>>(Opart, Mpart, Lpart, (float*)d_out);
}

// Round 5
// 179.741 us; speedup vs baseline: 1.3689x; 1.1367x over previous
//
#include <hip/hip_runtime.h>
#include <hip/hip_bf16.h>

typedef __attribute__((ext_vector_type(8))) short short8;
typedef __attribute__((ext_vector_type(4))) float f32x4;
typedef __attribute__((ext_vector_type(16))) float f32x16;
typedef unsigned short u16;

#define L2E 1.4426950408889634f

__device__ __forceinline__ u16 f2bf(float x) {
    union { float f; unsigned u; } v; v.f = x;
    return (u16)((v.u + 0x7FFFu + ((v.u >> 16) & 1u)) >> 16);
}

__device__ __forceinline__ void gl_lds16(const void* g, void* l) {
    __builtin_amdgcn_global_load_lds(
        (const __attribute__((address_space(1))) unsigned int*)g,
        (__attribute__((address_space(3))) unsigned int*)l, 16, 0, 0);
}

__device__ __forceinline__ int cvtpk(float lo, float hi) {
    int r;
    asm("v_cvt_pk_bf16_f32 %0, %1, %2" : "=v"(r) : "v"(lo), "v"(hi));
    return r;
}

// a' = {a.lanes0-31, b.lanes0-31}; b' = {a.lanes32-63, b.lanes32-63}
__device__ __forceinline__ void plswap(int& a, int& b) {
    asm volatile("v_permlane32_swap_b32 %0, %1" : "+v"(a), "+v"(b));
}

// ---------------------------------------------------------------------------
// Workspace layout (bytes):
//  wtq   @ 0        : 64*1024*2   = 131072
//  wtkv  @ 131072   : 128*1024*2  = 262144  (rows 0-63 = Wk^T, 64-127 = Wv^T)
//  Qb    @ 393216   : 4*2048*64*2 = 1048576 (scale 0.125 + bias folded)
//  Kb    @ 1441792  : 4*4096*64*2 = 2097152
//  Vtb   @ 3538944  : 4*64*4096*2 = 2097152 ([b][d][s])
//  OpT   @ 5636096  : NS*4*64*2048*4        ([ks][b][d][q] partial O^T)
//  Mpart @ OPT+sz   : NS*8192*4
//  Lpart @ ...      : NS*8192*4
//  NS=8 total: 22937600 ; NS=4 total: 14286848
// ---------------------------------------------------------------------------
#define WTQ_OFF   0
#define WTKV_OFF  131072
#define Q_OFF     393216
#define K_OFF     1441792
#define VT_OFF    3538944
#define OPT_OFF   5636096

// ---------------------------------------------------------------------------
// prep2: W [1024][64] f32 -> W^T [64][1024] bf16, coalesced via LDS tile.
// ---------------------------------------------------------------------------
__global__ __launch_bounds__(256) void prep2(
    const float* __restrict__ Wq, const float* __restrict__ Wk,
    const float* __restrict__ Wv, u16* __restrict__ wtq, u16* __restrict__ wtkv)
{
    __shared__ u16 tile[64][66];
    const int t = threadIdx.x;
    const int mat = blockIdx.x >> 4, kc = blockIdx.x & 15;
    const float* src = (mat == 0) ? Wq : ((mat == 1) ? Wk : Wv);
    u16* dst = (mat == 0) ? wtq : (wtkv + ((mat == 2) ? 64 * 1024 : 0));
    #pragma unroll
    for (int c = 0; c < 4; ++c) {
        int id = t + c * 256;
        int r = id >> 4, c4 = id & 15;
        float4 v = *(const float4*)(src + (size_t)(kc * 64 + r) * 64 + c4 * 4);
        tile[r][c4 * 4 + 0] = f2bf(v.x);
        tile[r][c4 * 4 + 1] = f2bf(v.y);
        tile[r][c4 * 4 + 2] = f2bf(v.z);
        tile[r][c4 * 4 + 3] = f2bf(v.w);
    }
    __syncthreads();
    int n = t >> 2, kch = t & 3;
    short8 v0, v1;
    #pragma unroll
    for (int j = 0; j < 8; ++j) {
        v0[j] = (short)tile[kch * 16 + j][n];
        v1[j] = (short)tile[kch * 16 + 8 + j][n];
    }
    u16* dp = dst + (size_t)n * 1024 + kc * 64 + kch * 16;
    *(short8*)dp = v0;
    *(short8*)(dp + 8) = v1;
}

// ---------------------------------------------------------------------------
// proj3: unified projection. Blocks 0..511: enc rows -> K + V^T.
// Blocks 512..767: dec rows -> Q (scale 0.125). BM=32, BK=64, 4 waves
// (wm = rows half, wn = cols half). 48 KB LDS dbuf -> 3 blocks/CU.
// ---------------------------------------------------------------------------
__global__ __launch_bounds__(256) void proj3(
    const float* __restrict__ enc, const float* __restrict__ dec,
    const u16* __restrict__ wtkv, const u16* __restrict__ wtq,
    const float* __restrict__ bk, const float* __restrict__ bv,
    const float* __restrict__ bq,
    u16* __restrict__ Kb, u16* __restrict__ Vtb, u16* __restrict__ Qb)
{
    constexpr int ABYTES = 32 * 64 * 4;      // 8 KB fp32 A tile
    constexpr int WBYTES = 128 * 64 * 2;     // 16 KB W tile
    constexpr int BUF = ABYTES + WBYTES;
    __shared__ __align__(16) char lds[2 * BUF];

    const int t = threadIdx.x, l = t & 63, w = t >> 6;
    const int wm = w >> 1, wn = w & 1;
    const bool is_enc = blockIdx.x < 512;
    const int r0 = is_enc ? blockIdx.x * 32 : (blockIdx.x - 512) * 32;
    const float* A = is_enc ? enc : dec;
    const u16* Wsrc = is_enc ? wtkv : wtq;

    f32x4 acc[4];
    #pragma unroll
    for (int n = 0; n < 4; ++n) acc[n] = (f32x4){0.f, 0.f, 0.f, 0.f};

    auto stage = [&](int buf, int kt) {
        char* Ab = lds + buf * BUF;
        char* Wb = Ab + ABYTES;
        const int k0 = kt * 64;
        #pragma unroll
        for (int c = 0; c < 2; ++c) {
            int id = t + c * 256;           // 0..511
            int row = id >> 4, sl = id & 15;
            gl_lds16(A + (size_t)(r0 + row) * 1024 + k0 + ((sl ^ (row & 7)) << 2),
                     Ab + id * 16);
        }
        #pragma unroll
        for (int c = 0; c < 4; ++c) {
            int id = t + c * 256;           // 0..1023
            int row = id >> 3, sl = id & 7;
            int wr = is_enc ? row : (row & 63);
            gl_lds16(Wsrc + (size_t)wr * 1024 + k0 + ((sl ^ (row & 7)) << 3),
                     Wb + id * 16);
        }
    };

    stage(0, 0);
    __syncthreads();
    int cur = 0;
    for (int kt = 0; kt < 16; ++kt) {
        if (kt < 15) stage(cur ^ 1, kt + 1);
        const char* Ab = lds + cur * BUF;
        const char* Wb = Ab + ABYTES;
        #pragma unroll
        for (int ks = 0; ks < 2; ++ks) {
            int arow = wm * 16 + (l & 15);
            int s0 = ks * 8 + (l >> 4) * 2;
            f32x4 lo = *(const f32x4*)(Ab + arow * 256 + ((s0 ^ (arow & 7)) << 4));
            f32x4 hi = *(const f32x4*)(Ab + arow * 256 + (((s0 + 1) ^ (arow & 7)) << 4));
            short8 afr;
            afr[0] = (short)f2bf(lo[0]); afr[1] = (short)f2bf(lo[1]);
            afr[2] = (short)f2bf(lo[2]); afr[3] = (short)f2bf(lo[3]);
            afr[4] = (short)f2bf(hi[0]); afr[5] = (short)f2bf(hi[1]);
            afr[6] = (short)f2bf(hi[2]); afr[7] = (short)f2bf(hi[3]);
            #pragma unroll
            for (int n = 0; n < 4; ++n) {
                int wrow = wn * 64 + n * 16 + (l & 15);
                int c8 = ks * 4 + (l >> 4);
                short8 bfr = *(const short8*)(Wb + wrow * 128 + ((c8 ^ (wrow & 7)) << 4));
                acc[n] = __builtin_amdgcn_mfma_f32_16x16x32_bf16(afr, bfr, acc[n], 0, 0, 0);
            }
        }
        __syncthreads();
        cur ^= 1;
    }

    // epilogue: lrow = wm*16 + (l>>4)*4 + i ; col = wn*64 + n*16 + (l&15)
    u16* Vs2 = (u16*)lds;    // [32][66] u16, reuses buf0
    if (is_enc) {
        if (wn == 0) {
            #pragma unroll
            for (int n = 0; n < 4; ++n) {
                int col = n * 16 + (l & 15);
                #pragma unroll
                for (int i = 0; i < 4; ++i) {
                    int lrow = wm * 16 + (l >> 4) * 4 + i;
                    Kb[(size_t)(r0 + lrow) * 64 + col] = f2bf(acc[n][i] + bk[col]);
                }
            }
        } else {
            #pragma unroll
            for (int n = 0; n < 4; ++n) {
                int d = n * 16 + (l & 15);
                #pragma unroll
                for (int i = 0; i < 4; ++i) {
                    int lrow = wm * 16 + (l >> 4) * 4 + i;
                    Vs2[lrow * 66 + d] = f2bf(acc[n][i] + bv[d]);
                }
            }
        }
        __syncthreads();
        int d = t >> 2, sch = t & 3;
        short8 v;
        #pragma unroll
        for (int j = 0; j < 8; ++j) v[j] = (short)Vs2[(sch * 8 + j) * 66 + d];
        int bb = r0 >> 12, s0r = r0 & 4095;
        *(short8*)(Vtb + ((size_t)(bb * 64 + d)) * 4096 + s0r + sch * 8) = v;
    } else {
        if (wn == 0) {
            #pragma unroll
            for (int n = 0; n < 4; ++n) {
                int col = n * 16 + (l & 15);
                #pragma unroll
                for (int i = 0; i < 4; ++i) {
                    int lrow = wm * 16 + (l >> 4) * 4 + i;
                    Qb[(size_t)(r0 + lrow) * 64 + col] =
                        f2bf((acc[n][i] + bq[col]) * 0.125f);
                }
            }
        }
    }
}

// ---------------------------------------------------------------------------
// attn3<NS>: swapped-operand flash attention, no LDS, 32x32x16 MFMA.
// Grid (16 qgroups, 4 batch, NS ksplit) x 256 thr; wave w owns q-tile
// blockIdx.x*4+w (32 q) and sweeps 4096/NS keys (tiles of 32).
// S^T = K·Q^T  (A=K row=key, B=Q col=q)  -> lane owns q = lane&31.
// Softmax fully in-register (16 keys/lane-half + one shfl_xor(32)).
// P -> bf16 B-frags via v_cvt_pk_bf16_f32 + v_permlane32_swap_b32 (T12).
// O^T += V^T·P (A=V^T row=d). Partials stored as O^T [ks][b][d][q].
// ---------------------------------------------------------------------------
template<int NS>
__global__ __launch_bounds__(256, 2) void attn3(
    const u16* __restrict__ Qb, const u16* __restrict__ Kb,
    const u16* __restrict__ Vtb, float* __restrict__ OpT,
    float* __restrict__ Mpart, float* __restrict__ Lpart)
{
    constexpr int SPAN = 4096 / NS;
    constexpr int NIT = SPAN / 64;
    const int t = threadIdx.x, l = t & 63, w = t >> 6;
    const int b = blockIdx.y, bz = blockIdx.z;
    const int q0 = (blockIdx.x * 4 + w) * 32;
    const int lq = l & 31, lh = l >> 5;

    // Q B-frags: col=q=lq, k = dt*16 + lh*8 + j
    short8 qf[4];
    #pragma unroll
    for (int dt = 0; dt < 4; ++dt)
        qf[dt] = *(const short8*)(Qb + (size_t)(b * 2048 + q0 + lq) * 64
                                  + dt * 16 + lh * 8);

    f32x16 o0, o1;
    #pragma unroll
    for (int r = 0; r < 16; ++r) { o0[r] = 0.f; o1[r] = 0.f; }
    float mrun = -INFINITY, lrun = 0.f;

    const size_t kbase = (size_t)b * 4096 * 64;
    const size_t vbase = (size_t)b * 64 * 4096;

    auto LOADT = [&](short8 (&kf)[4], short8 (&vf)[2][2], int kt) {
        #pragma unroll
        for (int dt = 0; dt < 4; ++dt)
            kf[dt] = *(const short8*)(Kb + kbase + (size_t)(kt + lq) * 64
                                      + dt * 16 + lh * 8);
        #pragma unroll
        for (int db = 0; db < 2; ++db)
            #pragma unroll
            for (int kh = 0; kh < 2; ++kh)
                vf[db][kh] = *(const short8*)(Vtb + vbase
                                              + (size_t)(db * 32 + lq) * 4096
                                              + kt + kh * 16 + lh * 8);
    };

    auto COMPUTE = [&](short8 (&kf)[4], short8 (&vf)[2][2]) {
        f32x16 s;
        #pragma unroll
        for (int r = 0; r < 16; ++r) s[r] = 0.f;
        #pragma unroll
        for (int dt = 0; dt < 4; ++dt)
            s = __builtin_amdgcn_mfma_f32_32x32x16_bf16(kf[dt], qf[dt], s, 0, 0, 0);
        // in-register max over 16 keys (half), then cross-half
        float m0 = fmaxf(fmaxf(s[0], s[1]), fmaxf(s[2], s[3]));
        float m1 = fmaxf(fmaxf(s[4], s[5]), fmaxf(s[6], s[7]));
        float m2 = fmaxf(fmaxf(s[8], s[9]), fmaxf(s[10], s[11]));
        float m3 = fmaxf(fmaxf(s[12], s[13]), fmaxf(s[14], s[15]));
        float pm = fmaxf(fmaxf(m0, m1), fmaxf(m2, m3));
        pm = fmaxf(pm, __shfl_xor(pm, 32));
        float mn = fmaxf(mrun, pm);
        float corr = exp2f((mrun - mn) * L2E);
        mrun = mn;
        float nm = -mn * L2E;
        float p[16];
        #pragma unroll
        for (int r = 0; r < 16; ++r) p[r] = exp2f(fmaf(s[r], L2E, nm));
        float rs = ((p[0] + p[1]) + (p[2] + p[3])) + ((p[4] + p[5]) + (p[6] + p[7]))
                 + ((p[8] + p[9]) + (p[10] + p[11])) + ((p[12] + p[13]) + (p[14] + p[15]));
        rs += __shfl_xor(rs, 32);
        lrun = lrun * corr + rs;
        o0 *= corr;
        o1 *= corr;
        // P (key-rows (r&3)+8*(r>>2)+4*lh, col q) -> B-frags, k = kh*16+lh*8+j
        short8 pb[2];
        #pragma unroll
        for (int kh = 0; kh < 2; ++kh) {
            int a0 = cvtpk(p[kh * 8 + 0], p[kh * 8 + 1]);
            int b0 = cvtpk(p[kh * 8 + 4], p[kh * 8 + 5]);
            int a1 = cvtpk(p[kh * 8 + 2], p[kh * 8 + 3]);
            int b1 = cvtpk(p[kh * 8 + 6], p[kh * 8 + 7]);
            plswap(a0, b0);   // a0 = {lo half keys +0,+1 | +8,+9}, b0 = {+4,+5 | +12,+13}
            plswap(a1, b1);
            union { int wd[4]; short8 v; } u;
            u.wd[0] = a0; u.wd[1] = a1; u.wd[2] = b0; u.wd[3] = b1;
            pb[kh] = u.v;
        }
        #pragma unroll
        for (int kh = 0; kh < 2; ++kh) {
            o0 = __builtin_amdgcn_mfma_f32_32x32x16_bf16(vf[0][kh], pb[kh], o0, 0, 0, 0);
            o1 = __builtin_amdgcn_mfma_f32_32x32x16_bf16(vf[1][kh], pb[kh], o1, 0, 0, 0);
        }
    };

    short8 kfA[4], vfA[2][2], kfB[4], vfB[2][2];
    const int kt0 = bz * SPAN;
    LOADT(kfA, vfA, kt0);
    for (int it = 0; it < NIT; ++it) {
        const int kt = kt0 + it * 64;
        LOADT(kfB, vfB, kt + 32);
        COMPUTE(kfA, vfA);
        if (it < NIT - 1) LOADT(kfA, vfA, kt + 64);
        COMPUTE(kfB, vfB);
    }

    // store unnormalized O^T partial + (M, L)
    const size_t obase = ((size_t)(bz * 4 + b) * 64) * 2048 + q0 + lq;
    #pragma unroll
    for (int r = 0; r < 16; ++r) {
        int drow = (r & 3) + 8 * (r >> 2) + 4 * lh;
        OpT[obase + (size_t)drow * 2048] = o0[r];
        OpT[obase + (size_t)(drow + 32) * 2048] = o1[r];
    }
    if (l < 32) {
        Mpart[bz * 8192 + b * 2048 + q0 + l] = mrun;
        Lpart[bz * 8192 + b * 2048 + q0 + l] = lrun;
    }
}

// ---------------------------------------------------------------------------
// combine3<NS>: merge NS key-splits of O^T, normalize, transpose to O[q][d].
// One block per (b, 32-q tile).
// ---------------------------------------------------------------------------
template<int NS>
__global__ __launch_bounds__(256) void combine3(
    const float* __restrict__ OpT, const float* __restrict__ Mpart,
    const float* __restrict__ Lpart, float* __restrict__ Out)
{
    __shared__ float wsh[NS][32];
    __shared__ float trans[32][72];
    const int t = threadIdx.x;
    const int b = blockIdx.x >> 6;
    const int q0 = (blockIdx.x & 63) * 32;

    if (t < 32) {
        int q = t;
        float m4[NS], M = -INFINITY;
        #pragma unroll
        for (int ks = 0; ks < NS; ++ks) {
            m4[ks] = Mpart[ks * 8192 + b * 2048 + q0 + q];
            M = fmaxf(M, m4[ks]);
        }
        float wv[NS], Lf = 0.f;
        #pragma unroll
        for (int ks = 0; ks < NS; ++ks) {
            wv[ks] = exp2f((m4[ks] - M) * L2E);
            Lf += Lpart[ks * 8192 + b * 2048 + q0 + q] * wv[ks];
        }
        float inv = 1.0f / Lf;
        #pragma unroll
        for (int ks = 0; ks < NS; ++ks) wsh[ks][q] = wv[ks] * inv;
    }
    __syncthreads();
    {
        int d = t >> 2, qc = (t & 3) * 8;
        float a8[8];
        #pragma unroll
        for (int j = 0; j < 8; ++j) a8[j] = 0.f;
        #pragma unroll
        for (int ks = 0; ks < NS; ++ks) {
            const float* p = OpT + (((size_t)(ks * 4 + b)) * 64 + d) * 2048 + q0 + qc;
            f32x4 x = *(const f32x4*)p;
            f32x4 y = *(const f32x4*)(p + 4);
            #pragma unroll
            for (int j = 0; j < 4; ++j) {
                a8[j]     += x[j] * wsh[ks][qc + j];
                a8[4 + j] += y[j] * wsh[ks][qc + 4 + j];
            }
        }
        #pragma unroll
        for (int j = 0; j < 8; ++j) trans[qc + j][d] = a8[j];
    }
    __syncthreads();
    {
        int q = t >> 3, dc = (t & 7) * 8;
        f32x4 x = *(const f32x4*)&trans[q][dc];
        f32x4 y = *(const f32x4*)&trans[q][dc + 4];
        float* dst = Out + ((size_t)(b * 2048 + q0 + q)) * 64 + dc;
        *(f32x4*)dst = x;
        *(f32x4*)(dst + 4) = y;
    }
}

extern "C" void kernel_launch(void* const* d_in, const int* in_sizes, int n_in,
                              void* d_out, int out_size, void* d_ws, size_t ws_size,
                              hipStream_t stream) {
    const float* enc = (const float*)d_in[0];   // [4,4096,1024]
    const float* dec = (const float*)d_in[1];   // [4,2048,1024]
    const float* Wq  = (const float*)d_in[2];
    const float* bq  = (const float*)d_in[3];
    const float* Wk  = (const float*)d_in[4];
    const float* bk  = (const float*)d_in[5];
    const float* Wv  = (const float*)d_in[6];
    const float* bv  = (const float*)d_in[7];

    char* ws = (char*)d_ws;
    u16* wtq   = (u16*)(ws + WTQ_OFF);
    u16* wtkv  = (u16*)(ws + WTKV_OFF);
    u16* Qb    = (u16*)(ws + Q_OFF);
    u16* Kb    = (u16*)(ws + K_OFF);
    u16* Vtb   = (u16*)(ws + VT_OFF);
    float* OpT = (float*)(ws + OPT_OFF);

    prep2<<<48, 256, 0, stream>>>(Wq, Wk, Wv, wtq, wtkv);
    proj3<<<768, 256, 0, stream>>>(enc, dec, wtkv, wtq, bk, bv, bq, Kb, Vtb, Qb);

    const size_t need8 = (size_t)OPT_OFF + 8ull * 4 * 64 * 2048 * 4 + 2ull * 8 * 8192 * 4;
    if (ws_size >= need8) {
        float* Mpart = (float*)(ws + OPT_OFF + 8ull * 4 * 64 * 2048 * 4);
        float* Lpart = Mpart + 8 * 8192;
        attn3<8><<<dim3(16, 4, 8), 256, 0, stream>>>(Qb, Kb, Vtb, OpT, Mpart, Lpart);
        combine3<8><<<256, 256, 0, stream>>>(OpT, Mpart, Lpart, (float*)d_out);
    } else {
        float* Mpart = (float*)(ws + OPT_OFF + 4ull * 4 * 64 * 2048 * 4);
        float* Lpart = Mpart + 4 * 8192;
        attn3<4><<<dim3(16, 4, 4), 256, 0, stream>>>(Qb, Kb, Vtb, OpT, Mpart, Lpart);
        combine3<4><<<256, 256, 0, stream>>>(OpT, Mpart, Lpart, (float*)d_out);
    }
}